// Round 8
// baseline (417.231 us; speedup 1.0000x reference)
//
#include <hip/hip_runtime.h>
#include <hip/hip_bf16.h>
#include <stdint.h>

#define VOCAB 10000
#define XDIM 128
#define HID 256
#define BATCH 128
#define SEQ 50
#define ROWS (BATCH * SEQ) /* 6400 */

// K3 tiling
#define BM 128
#define BN 256
#define BK 64
#define NTM 50 /* 6400/128 */
#define NTN 40 /* ceil(10000/256) */

// fused K0+K1 grid split
#define K1_BLOCKS (ROWS / 8)                 /* 800 */
#define K0_BLOCKS ((VOCAB * HID) / (256 * 8)) /* 1250 */

// K2 MFMA geometry
#define K2G 16                    /* batches per block */
#define K2_BLOCKS (BATCH / K2G)   /* 8 */
#define HPAD 264                  /* 256 + 8 bf16 pad: row stride 528B, 16B-mult */

typedef __bf16 bf16x8 __attribute__((ext_vector_type(8)));
typedef float f32x4 __attribute__((ext_vector_type(4)));

__device__ __forceinline__ uint16_t f2bf(float f) {
    union { float f; uint32_t i; } v;
    v.f = f;
    uint32_t x = v.i;
    return (uint16_t)((x + 0x7fffu + ((x >> 16) & 1u)) >> 16); // RNE
}
__device__ __forceinline__ float bf2f(uint16_t b) {
    union { uint32_t u; float f; } v;
    v.u = (uint32_t)b << 16;
    return v.f;
}

// ---------------------------------------------------------------------------
// K01: fused W_aff cast (K0) + xin projection (K1). (unchanged from R7)
// ---------------------------------------------------------------------------
__global__ __launch_bounds__(256, 2) void k01_fused(
    const int* __restrict__ x, const float* __restrict__ emb,
    const float* __restrict__ Wih, const float* __restrict__ bih,
    const float* __restrict__ bhh, float* __restrict__ xin,
    const float* __restrict__ Waff, uint16_t* __restrict__ Wb) {
    __shared__ __align__(16) float es[8][XDIM];
    const int tid = threadIdx.x;

    if (blockIdx.x >= K1_BLOCKS) {
        // ---- K0 path: cast W_aff fp32 -> bf16, 8 elems/thread ----
        const int i = ((blockIdx.x - K1_BLOCKS) * 256 + tid) * 8;
        float4 a = *(const float4*)(Waff + i);
        float4 b = *(const float4*)(Waff + i + 4);
        uint16_t t[8];
        t[0] = f2bf(a.x); t[1] = f2bf(a.y); t[2] = f2bf(a.z); t[3] = f2bf(a.w);
        t[4] = f2bf(b.x); t[5] = f2bf(b.y); t[6] = f2bf(b.z); t[7] = f2bf(b.w);
        *(uint4*)(Wb + i) = *(const uint4*)t;
        return;
    }

    // ---- K1 path ----
    const int r0 = blockIdx.x * 8;
    {
        const int row = tid >> 5, c = tid & 31;
        const int tok = x[r0 + row];
        *(float4*)&es[row][c * 4] = *(const float4*)(emb + tok * XDIM + c * 4);
    }
    __syncthreads();

    const int j = tid;
    float wf[XDIM];
    const float4* wrow = (const float4*)(Wih + j * XDIM);
#pragma unroll
    for (int c = 0; c < 32; ++c) *(float4*)&wf[c * 4] = wrow[c];
    const float bias = bih[j] + bhh[j];

    float acc[8];
#pragma unroll
    for (int r = 0; r < 8; ++r) acc[r] = bias;
#pragma unroll
    for (int k4 = 0; k4 < 32; ++k4) {
#pragma unroll
        for (int r = 0; r < 8; ++r) {
            float4 e = *(const float4*)&es[r][k4 * 4];
            acc[r] += e.x * wf[k4 * 4 + 0] + e.y * wf[k4 * 4 + 1] +
                      e.z * wf[k4 * 4 + 2] + e.w * wf[k4 * 4 + 3];
        }
    }
#pragma unroll
    for (int r = 0; r < 8; ++r) xin[(r0 + r) * HID + j] = acc[r];
}

// ---------------------------------------------------------------------------
// K2v5: MFMA recurrence. 16 batches/block (8 blocks, 512 thr = 8 waves).
// Step: C[16 batch x 256 j] = H(bf16 hi/lo, LDS dbuf) . W_hh^T(bf16 hi/lo,
// register-resident). 3 passes (Whi*Hhi + Whi*Hlo + Wlo*Hhi) keep fp32-grade
// accuracy (error ~2^-16/step). Fragment recipe identical to K3's verified
// mapping: A-row=batch<->l15, B-row=j<->l15, C row=quad*4+r, col=l15.
// ONE barrier/step (h double-buffered). Replaces the broadcast-ds_read
// structure (256 LDS insts/step, ~4500 cyc/step) with MFMA ingest at
// 1KB/inst (~128 reads + 128 b16 writes/step).
// Wave w owns j in [w*32, w*32+32) as 2 n-tiles of 16.
// ---------------------------------------------------------------------------
__global__ __launch_bounds__(512, 2) void k2_rnn(
    const float* __restrict__ xin, const float* __restrict__ Whh,
    uint16_t* __restrict__ hs) {
    // [buf][hi/lo][batch][HPAD]
    __shared__ __align__(16) uint16_t H[2][2][K2G][HPAD];  // 33 KB

    const int tid = threadIdx.x;
    const int wave = tid >> 6, ln = tid & 63;
    const int quad = ln >> 4, l15 = ln & 15;
    const int g0 = blockIdx.x * K2G;   // batch base

    // ---- load W_hh fragments into registers, split hi/lo ----
    bf16x8 whi[2][8], wlo[2][8];
#pragma unroll
    for (int nt = 0; nt < 2; ++nt) {
        const int j = wave * 32 + nt * 16 + l15;
#pragma unroll
        for (int ks = 0; ks < 8; ++ks) {
            float w[8];
            const float* wp = Whh + (size_t)j * HID + ks * 32 + quad * 8;
            *(float4*)&w[0] = *(const float4*)(wp);
            *(float4*)&w[4] = *(const float4*)(wp + 4);
            uint16_t hb_[8], lb_[8];
#pragma unroll
            for (int v = 0; v < 8; ++v) {
                hb_[v] = f2bf(w[v]);
                lb_[v] = f2bf(w[v] - bf2f(hb_[v]));
            }
            whi[nt][ks] = *(const bf16x8*)hb_;
            wlo[nt][ks] = *(const bf16x8*)lb_;
        }
    }

    // ---- t = 0: h1 = tanh(xin[:,0,:]) (h0 = 0, xin includes both biases) ----
#pragma unroll
    for (int nt = 0; nt < 2; ++nt) {
        const int j = wave * 32 + nt * 16 + l15;
#pragma unroll
        for (int r = 0; r < 4; ++r) {
            const int lb = quad * 4 + r;                   // local batch
            const size_t row = (size_t)(g0 + lb) * SEQ + 0;
            const float hv = tanhf(xin[row * HID + j]);
            const uint16_t hi = f2bf(hv);
            H[0][0][lb][j] = hi;
            H[0][1][lb][j] = f2bf(hv - bf2f(hi));
            hs[row * HID + j] = hi;
        }
    }
    __syncthreads();

    // ---- t = 1 .. SEQ-1 ----
    for (int t = 1; t < SEQ; ++t) {
        const int cur = (t - 1) & 1, nxt = t & 1;

        // xin loads issued first: full MFMA phase to cover latency
        float xv[2][4];
#pragma unroll
        for (int nt = 0; nt < 2; ++nt) {
            const int j = wave * 32 + nt * 16 + l15;
#pragma unroll
            for (int r = 0; r < 4; ++r) {
                const size_t row = (size_t)(g0 + quad * 4 + r) * SEQ + t;
                xv[nt][r] = xin[row * HID + j];
            }
        }

        f32x4 c[2] = {(f32x4)0.0f, (f32x4)0.0f};
#pragma unroll
        for (int ks = 0; ks < 8; ++ks) {
            const bf16x8 ah =
                *(const bf16x8*)&H[cur][0][l15][ks * 32 + quad * 8];
            const bf16x8 al =
                *(const bf16x8*)&H[cur][1][l15][ks * 32 + quad * 8];
#pragma unroll
            for (int nt = 0; nt < 2; ++nt) {
                c[nt] = __builtin_amdgcn_mfma_f32_16x16x32_bf16(
                    ah, whi[nt][ks], c[nt], 0, 0, 0);
                c[nt] = __builtin_amdgcn_mfma_f32_16x16x32_bf16(
                    al, whi[nt][ks], c[nt], 0, 0, 0);
                c[nt] = __builtin_amdgcn_mfma_f32_16x16x32_bf16(
                    ah, wlo[nt][ks], c[nt], 0, 0, 0);
            }
        }

        // epilogue: h = tanh(C + xin); publish hi/lo to next buffer + hs
#pragma unroll
        for (int nt = 0; nt < 2; ++nt) {
            const int j = wave * 32 + nt * 16 + l15;
#pragma unroll
            for (int r = 0; r < 4; ++r) {
                const int lb = quad * 4 + r;
                const float hv = tanhf(c[nt][r] + xv[nt][r]);
                const uint16_t hi = f2bf(hv);
                H[nxt][0][lb][j] = hi;
                H[nxt][1][lb][j] = f2bf(hv - bf2f(hi));
                hs[((size_t)(g0 + lb) * SEQ + t) * HID + j] = hi;
            }
        }
        __syncthreads();  // one barrier/step: publishes H[nxt], and step t+1's
                          // writes target H[cur] whose reads are now drained
    }
}

// ---------------------------------------------------------------------------
// K3v5: staged main loop + LDS-transposed nt epilogue. (unchanged from R7)
// ---------------------------------------------------------------------------
__global__ __launch_bounds__(256, 2) void k3_gemm(
    const uint16_t* __restrict__ A,   // hs  [6400][256] bf16
    const uint16_t* __restrict__ Bw,  // W_aff [10000][256] bf16
    const float* __restrict__ baff,   // [10000] fp32
    float* __restrict__ out) {
    __shared__ __align__(16) char smem[49152];       // 48 KB
    uint16_t* As = (uint16_t*)smem;                  // [BM*BK] 16 KB
    uint16_t* Bs = (uint16_t*)(smem + BM * BK * 2);  // [BN*BK] 32 KB

    const int bid0 = blockIdx.x;
    const int bid = (bid0 & 7) * ((NTM * NTN) / 8) + (bid0 >> 3);
    const int bm = bid % NTM, bn = bid / NTM;
    const int m0 = bm * BM, n0 = bn * BN;
    const int tid = threadIdx.x;
    const int wv = tid >> 6, ln = tid & 63;
    const int wm = wv & 1, wn = wv >> 1;
    const int quad = ln >> 4, l15 = ln & 15;

    f32x4 acc[4][8];
#pragma unroll
    for (int i = 0; i < 4; ++i)
#pragma unroll
        for (int jj = 0; jj < 8; ++jj) acc[i][jj] = (f32x4)0.0f;

    const int lrow = ln >> 3;
    const int gsw = ((ln & 7) ^ lrow) * 8;

    for (int kt = 0; kt < 4; ++kt) {
        const int k0 = kt * BK;
#pragma unroll
        for (int i = 0; i < 4; ++i) {
            const int ci = wv * 4 + i;
            const uint16_t* g = A + (size_t)(m0 + ci * 8 + lrow) * HID + k0 + gsw;
            __builtin_amdgcn_global_load_lds(
                (const __attribute__((address_space(1))) void*)g,
                (__attribute__((address_space(3))) void*)(As + ci * 512), 16, 0, 0);
        }
#pragma unroll
        for (int i = 0; i < 8; ++i) {
            const int ci = wv * 8 + i;
            int n = n0 + ci * 8 + lrow;
            if (n > VOCAB - 1) n = VOCAB - 1;
            const uint16_t* g = Bw + (size_t)n * HID + k0 + gsw;
            __builtin_amdgcn_global_load_lds(
                (const __attribute__((address_space(1))) void*)g,
                (__attribute__((address_space(3))) void*)(Bs + ci * 512), 16, 0, 0);
        }
        __syncthreads();

#pragma unroll
        for (int kk = 0; kk < 2; ++kk) {
            const int gk = kk * 4 + quad;
            bf16x8 af[4], bf[8];
#pragma unroll
            for (int tm = 0; tm < 4; ++tm) {
                const int R = wm * 64 + tm * 16 + l15;
                af[tm] = *(const bf16x8*)&As[R * 64 + ((gk ^ (R & 7)) * 8)];
            }
#pragma unroll
            for (int tn = 0; tn < 8; ++tn) {
                const int R = wn * 128 + tn * 16 + l15;
                bf[tn] = *(const bf16x8*)&Bs[R * 64 + ((gk ^ (R & 7)) * 8)];
            }
#pragma unroll
            for (int tm = 0; tm < 4; ++tm)
#pragma unroll
                for (int tn = 0; tn < 8; ++tn)
                    acc[tm][tn] = __builtin_amdgcn_mfma_f32_16x16x32_bf16(
                        af[tm], bf[tn], acc[tm][tn], 0, 0, 0);
        }
        __syncthreads();
    }

    float* csw = (float*)smem + wv * 16 * 132;
    float bias[8];
#pragma unroll
    for (int tn = 0; tn < 8; ++tn) {
        int n = n0 + wn * 128 + tn * 16 + l15;
        bias[tn] = baff[n > VOCAB - 1 ? VOCAB - 1 : n];
    }
#pragma unroll
    for (int tm = 0; tm < 4; ++tm) {
#pragma unroll
        for (int tn = 0; tn < 8; ++tn)
#pragma unroll
            for (int r = 0; r < 4; ++r)
                csw[(quad * 4 + r) * 132 + tn * 16 + l15] =
                    acc[tm][tn][r] + bias[tn];
        __syncthreads();
#pragma unroll
        for (int it = 0; it < 8; ++it) {
            const int row = it * 2 + (ln >> 5);
            const int c4 = (ln & 31) * 4;
            const f32x4 v = *(const f32x4*)&csw[row * 132 + c4];
            const int gm = m0 + wm * 64 + tm * 16 + row;
            const int gn = n0 + wn * 128 + c4;
            if (gn < VOCAB)
                __builtin_nontemporal_store(
                    v, (f32x4*)(out + (size_t)gm * VOCAB + gn));
        }
        __syncthreads();
    }
}

extern "C" void kernel_launch(void* const* d_in, const int* in_sizes, int n_in,
                              void* d_out, int out_size, void* d_ws, size_t ws_size,
                              hipStream_t stream) {
    const int* x = (const int*)d_in[0];
    const float* emb = (const float*)d_in[1];
    const float* Wih = (const float*)d_in[2];
    const float* Whh = (const float*)d_in[3];
    const float* bih = (const float*)d_in[4];
    const float* bhh = (const float*)d_in[5];
    const float* Waff = (const float*)d_in[6];
    const float* baff = (const float*)d_in[7];

    float* xin = (float*)d_ws;                                         // 6.55 MB
    uint16_t* hsb = (uint16_t*)((char*)d_ws + (size_t)ROWS * HID * 4); // 3.28 MB
    uint16_t* Wb = hsb + (size_t)ROWS * HID;                           // 5.12 MB
    float* out = (float*)d_out;

    k01_fused<<<K1_BLOCKS + K0_BLOCKS, 256, 0, stream>>>(
        x, emb, Wih, bih, bhh, xin, Waff, Wb);
    k2_rnn<<<K2_BLOCKS, 512, 0, stream>>>(xin, Whh, hsb);
    k3_gemm<<<NTM * NTN, 256, 0, stream>>>(hsb, Wb, baff, out);
}